// Round 11
// baseline (51791.754 us; speedup 1.0000x reference)
//
#include <hip/hip_runtime.h>
#include <cmath>

#define NB   256
#define NT   64
#define DATA 256
#define DD   264
#define WID  256
#define NSUB 4
#define NTH  512
#define PI_F 3.14159265358979323846f

// ---- d_ws word offsets ----
#define WS_W1T  0                        // fp32 [256][256] k-major W1 (rows 0..127 used)
#define WS_W2T  (WS_W1T + 65536)         // fp32 [256][256] k-major W2
#define WS_W0B  (WS_W2T + 65536)         // u32 [272][128]: bf16 pairs, W0T row k, cols (2m,2m+1)
#define WS_W1HB (WS_W0B + 272 * 128)     // u32 [128][128]: bf16 pairs, W1T rows 128..255
#define WS_W3B  (WS_W1HB + 128 * 128)    // u32 [256][136]: bf16 pairs, W3T cols 0..271 (pad 0)

// ---- LDS word offsets (R9 layout: 0 bank conflicts measured) ----
#define L_W1LO 0                         // fp32 [128][256] W1T rows 0..127
#define L_PS   (L_W1LO + 128 * 256)      // fp32 [8][272]
#define L_Y    (L_PS + 8 * 272)          // 272 (pads 0)
#define L_IN   (L_Y + 272)               // 272 (pads 0)
#define L_ACC  (L_IN + 272)
#define L_HA   (L_ACC + 272)
#define L_HB   (L_HA + 272)
#define L_B0   (L_HB + 272)              // 256
#define L_B1   (L_B0 + 256)              // 256
#define L_B2   (L_B1 + 256)              // 256
#define L_B3   (L_B2 + 256)              // 272
#define LDS_FLOATS (L_B3 + 272)          // 37344 words = 149,376 B -> 1 block/CU

#define FMA4(acc, wv, fk)                                                     \
  acc.x = fmaf((wv).x, (fk), acc.x);                                          \
  acc.y = fmaf((wv).y, (fk), acc.y);                                          \
  acc.z = fmaf((wv).z, (fk), acc.z);                                          \
  acc.w = fmaf((wv).w, (fk), acc.w);

#define UPK(u, f0, f1)                                                        \
  const float f0 = __uint_as_float((u) << 16);                                \
  const float f1 = __uint_as_float((u) & 0xffff0000u);

__device__ __forceinline__ unsigned bf16rn(float f) {
  unsigned u = __float_as_uint(f);
  return (u + 0x7fffu + ((u >> 16) & 1u)) >> 16;   // RNE
}
__device__ __forceinline__ unsigned pk2(float lo, float hi) {
  return bf16rn(lo) | (bf16rn(hi) << 16);
}

__global__ void prep(const float* __restrict__ W0, const float* __restrict__ W1,
                     const float* __restrict__ W2, const float* __restrict__ W3,
                     float* __restrict__ wsf) {
  unsigned* wsu = (unsigned*)wsf;
  int tid = blockIdx.x * blockDim.x + threadIdx.x;
  int stride = gridDim.x * blockDim.x;
  for (int i = tid; i < 65536; i += stride) {         // fp32 W1T, W2T
    int k = i >> 8, j = i & 255;
    wsf[WS_W1T + i] = W1[j * 256 + k];
    wsf[WS_W2T + i] = W2[j * 256 + k];
  }
  for (int i = tid; i < 272 * 128; i += stride) {     // W0T bf16 [272][128]
    int k = i >> 7, m = i & 127;                      // cols 2m, 2m+1
    float lo = 0.f, hi = 0.f;
    if (k < DD) { lo = W0[(2 * m) * DD + k]; hi = W0[(2 * m + 1) * DD + k]; }
    wsu[WS_W0B + i] = pk2(lo, hi);
  }
  for (int i = tid; i < 128 * 128; i += stride) {     // W1T rows 128.. bf16
    int k2 = i >> 7, m = i & 127;
    wsu[WS_W1HB + i] = pk2(W1[(2 * m) * 256 + 128 + k2],
                           W1[(2 * m + 1) * 256 + 128 + k2]);
  }
  for (int i = tid; i < 256 * 136; i += stride) {     // W3T bf16 [256][136]
    int k = i / 136, m = i - k * 136;
    int j0 = 2 * m, j1 = 2 * m + 1;
    float lo = (j0 < DD) ? W3[j0 * 256 + k] : 0.f;
    float hi = (j1 < DD) ? W3[j1 * 256 + k] : 0.f;
    wsu[WS_W3B + i] = pk2(lo, hi);
  }
}

// amdgpu_waves_per_eu(2,2): pin EXACTLY 2 waves/EU -> 256-VGPR cap, so the
// 128-reg W2 cache stays in registers. launch_bounds' 2nd arg is only a MIN
// waves/EU; R4-R10 showed the compiler then picks 4/EU -> 128-cap -> spill.
__global__ __launch_bounds__(NTH)
__attribute__((amdgpu_waves_per_eu(2, 2)))
void node_integrate(
    const float* __restrict__ ts, const float* __restrict__ xs,
    const float* __restrict__ a_sample,
    const float* __restrict__ b0g, const float* __restrict__ b1g,
    const float* __restrict__ b2g, const float* __restrict__ b3g,
    const float* __restrict__ ws, float* __restrict__ out) {
  extern __shared__ float sm[];
  const unsigned* wsu = (const unsigned*)ws;
  const int b   = blockIdx.x;
  const int tid = threadIdx.x;
  const int w   = tid >> 6;
  const int l   = tid & 63;

  for (int i = tid; i < 256; i += NTH) {
    sm[L_B0 + i] = b0g[i];
    sm[L_B1 + i] = b1g[i];
    sm[L_B2 + i] = b2g[i];
  }
  for (int i = tid; i < 272; i += NTH) sm[L_B3 + i] = (i < DD) ? b3g[i] : 0.f;
  {
    const float4* src = (const float4*)(ws + WS_W1T);   // rows 0..127
    float4* dst = (float4*)(sm + L_W1LO);
    for (int i = tid; i < 128 * 64; i += NTH) dst[i] = src[i];
  }
  float4 w2r[32];
  {
    const float4* w2t4 = (const float4*)(ws + WS_W2T);
#pragma unroll
    for (int i = 0; i < 32; ++i) w2r[i] = w2t4[(w + 8 * i) * 64 + l];
  }
  {
    const float sc = a_sample[b] * expf(-0.1f * ts[0]);
    for (int i = tid; i < 272; i += NTH) {
      float v = 0.f;
      if (i < DATA) v = sc * sinf(PI_F * xs[(size_t)b * DATA + i]);
      sm[L_Y + i]  = v;
      sm[L_IN + i] = 0.f;
    }
  }
  __syncthreads();

  if (tid < DATA) out[((size_t)b * NT) * DATA + tid] = sm[L_Y + tid];

  float4* ps4 = (float4*)(sm + L_PS);
  const uint2* w0b2 = (const uint2*)(wsu + WS_W0B);    // [272][64] uint2
  const uint2* w1h2 = (const uint2*)(wsu + WS_W1HB);   // [128][64] uint2
  const uint2* w3b2 = (const uint2*)(wsu + WS_W3B);    // [256][68] uint2

#pragma unroll 1
  for (int t = 0; t < NT - 1; ++t) {
    const float dt = ts[t + 1] - ts[t];
    const float h  = dt * (1.0f / NSUB);
#pragma unroll 1
    for (int sub = 0; sub < NSUB; ++sub) {
#pragma unroll 1
      for (int st = 0; st < 3; ++st) {
        const float* finp = sm + ((st == 0) ? L_Y : L_IN);

        // ---- L0: hA = tanh(W0 @ fin + b0); streamed bf16, K=272(pad)
        {
          float4 acc; acc.x = acc.y = acc.z = acc.w = 0.f;
#pragma unroll
          for (int i = 0; i < 34; ++i) {
            const int k = w + 8 * i;            // < 272
            const uint2 u = w0b2[k * 64 + l];   // cols 4l..4l+3
            const float fk = finp[k];
            UPK(u.x, c0, c1) UPK(u.y, c2, c3)
            acc.x = fmaf(c0, fk, acc.x); acc.y = fmaf(c1, fk, acc.y);
            acc.z = fmaf(c2, fk, acc.z); acc.w = fmaf(c3, fk, acc.w);
          }
          ps4[w * 68 + l] = acc;
        }
        __syncthreads();
        if (tid < 256) {
          float sv = sm[L_B0 + tid];
#pragma unroll
          for (int ww = 0; ww < 8; ++ww) sv += sm[L_PS + ww * 272 + tid];
          sm[L_HA + tid] = tanhf(sv);
        }
        __syncthreads();

        // ---- L1: k<128 fp32 LDS, k>=128 bf16 stream
        {
          float4 acc; acc.x = acc.y = acc.z = acc.w = 0.f;
          const float4* w1lo4 = (const float4*)(sm + L_W1LO);
#pragma unroll
          for (int i = 0; i < 16; ++i) {
            const int k = w + 8 * i;
            const float fk = sm[L_HA + k];
            const float4 wv = w1lo4[k * 64 + l];
            FMA4(acc, wv, fk)
          }
#pragma unroll
          for (int i = 0; i < 16; ++i) {
            const int k2 = w + 8 * i;
            const uint2 u = w1h2[k2 * 64 + l];
            const float fk = sm[L_HA + 128 + k2];
            UPK(u.x, c0, c1) UPK(u.y, c2, c3)
            acc.x = fmaf(c0, fk, acc.x); acc.y = fmaf(c1, fk, acc.y);
            acc.z = fmaf(c2, fk, acc.z); acc.w = fmaf(c3, fk, acc.w);
          }
          ps4[w * 68 + l] = acc;
        }
        __syncthreads();
        if (tid < 256) {
          float sv = sm[L_B1 + tid];
#pragma unroll
          for (int ww = 0; ww < 8; ++ww) sv += sm[L_PS + ww * 272 + tid];
          sm[L_HB + tid] = tanhf(sv);
        }
        __syncthreads();

        // ---- L2: all-register fp32 W2
        {
          float4 acc; acc.x = acc.y = acc.z = acc.w = 0.f;
#pragma unroll
          for (int i = 0; i < 32; ++i) {
            const float fk = sm[L_HB + w + 8 * i];
            FMA4(acc, w2r[i], fk)
          }
          ps4[w * 68 + l] = acc;
        }
        __syncthreads();
        if (tid < 256) {
          float sv = sm[L_B2 + tid];
#pragma unroll
          for (int ww = 0; ww < 8; ++ww) sv += sm[L_PS + ww * 272 + tid];
          sm[L_HA + tid] = tanhf(sv);
        }
        __syncthreads();

        // ---- L3: streamed bf16 [256][68] uint2 rows (cols 0..271, pad 0)
        {
          float4 acc;  acc.x = acc.y = acc.z = acc.w = 0.f;
          float4 accx; accx.x = accx.y = accx.z = accx.w = 0.f;
#pragma unroll
          for (int i = 0; i < 32; ++i) {
            const int k = w + 8 * i;
            const float fk = sm[L_HA + k];
            const uint2 u = w3b2[k * 68 + l];            // cols 4l..4l+3
            UPK(u.x, c0, c1) UPK(u.y, c2, c3)
            acc.x = fmaf(c0, fk, acc.x); acc.y = fmaf(c1, fk, acc.y);
            acc.z = fmaf(c2, fk, acc.z); acc.w = fmaf(c3, fk, acc.w);
            if (l < 4) {
              const uint2 ux = w3b2[k * 68 + 64 + l];    // cols 256..271
              UPK(ux.x, d0, d1) UPK(ux.y, d2, d3)
              accx.x = fmaf(d0, fk, accx.x); accx.y = fmaf(d1, fk, accx.y);
              accx.z = fmaf(d2, fk, accx.z); accx.w = fmaf(d3, fk, accx.w);
            }
          }
          ps4[w * 68 + l] = acc;
          if (l < 4) ps4[w * 68 + 64 + l] = accx;
        }
        __syncthreads();
        if (tid < DD) {
          float kv = sm[L_B3 + tid];
#pragma unroll
          for (int ww = 0; ww < 8; ++ww) kv += sm[L_PS + ww * 272 + tid];
          if (st == 0) {
            sm[L_ACC + tid] = (2.0f / 9.0f) * kv;
            sm[L_IN + tid]  = sm[L_Y + tid] + 0.5f * h * kv;
          } else if (st == 1) {
            sm[L_ACC + tid] += (1.0f / 3.0f) * kv;
            sm[L_IN + tid]   = sm[L_Y + tid] + 0.75f * h * kv;
          } else {
            sm[L_Y + tid] += h * (sm[L_ACC + tid] + (4.0f / 9.0f) * kv);
          }
        }
        __syncthreads();
      }
    }
    if (tid < DATA) out[((size_t)b * NT + (t + 1)) * DATA + tid] = sm[L_Y + tid];
  }
}

extern "C" void kernel_launch(void* const* d_in, const int* in_sizes, int n_in,
                              void* d_out, int out_size, void* d_ws, size_t ws_size,
                              hipStream_t stream) {
  const float* ts = (const float*)d_in[0];
  const float* xs = (const float*)d_in[1];
  const float* a  = (const float*)d_in[2];
  const float* W0 = (const float*)d_in[3];
  const float* b0 = (const float*)d_in[4];
  const float* W1 = (const float*)d_in[5];
  const float* b1 = (const float*)d_in[6];
  const float* W2 = (const float*)d_in[7];
  const float* b2 = (const float*)d_in[8];
  const float* W3 = (const float*)d_in[9];
  const float* b3 = (const float*)d_in[10];
  float* ws  = (float*)d_ws;
  float* out = (float*)d_out;

  const size_t lds_bytes = LDS_FLOATS * sizeof(float);
  hipFuncSetAttribute(reinterpret_cast<const void*>(node_integrate),
                      hipFuncAttributeMaxDynamicSharedMemorySize,
                      (int)lds_bytes);

  hipLaunchKernelGGL(prep, dim3(256), dim3(256), 0, stream, W0, W1, W2, W3, ws);
  hipLaunchKernelGGL(node_integrate, dim3(NB), dim3(NTH), lds_bytes, stream,
                     ts, xs, a, b0, b1, b2, b3, ws, out);
}

// Round 13
// 40055.405 us; speedup vs baseline: 1.2930x; 1.2930x over previous
//
#include <hip/hip_runtime.h>
#include <cmath>

#define NB   256
#define NT   64
#define DATA 256
#define DD   264
#define NSUB 4
#define NTH  1024
#define NW   16
#define PI_F 3.14159265358979323846f

// ---- d_ws u32 offsets: bf16-pair packed, k-major. u32 index m = cols (2m,2m+1)
#define WS_W0B  0                        // [272][128] W0T (rows k>=264 zero)
#define WS_W1B  (WS_W0B + 272 * 128)     // [256][128] W1T
#define WS_W2B  (WS_W1B + 256 * 128)     // [256][128] W2T
#define WS_W3B  (WS_W2B + 256 * 128)     // [256][136] W3T cols 0..271 (>=264 zero)

// ---- LDS word offsets ----
#define L_W1B  0                         // [256][128] u32 bf16 W1T = 128 KB
#define L_PS   (L_W1B + 256 * 128)       // fp32 [16][272]
#define L_Y    (L_PS + NW * 272)         // 272 (pads 0)
#define L_IN   (L_Y + 272)               // 272 (pads 0)
#define L_ACC  (L_IN + 272)
#define L_HA   (L_ACC + 272)
#define L_HB   (L_HA + 272)
#define L_B0   (L_HB + 272)              // 256
#define L_B1   (L_B0 + 256)              // 256
#define L_B2   (L_B1 + 256)              // 256
#define L_B3   (L_B2 + 256)              // 272
#define LDS_WORDS (L_B3 + 272)           // 39520 words = 158,080 B -> 1 block/CU

#define UPK(u, f0, f1)                                                        \
  const float f0 = __uint_as_float((u) << 16);                                \
  const float f1 = __uint_as_float((u) & 0xffff0000u);

__device__ __forceinline__ unsigned bf16rn(float f) {
  unsigned u = __float_as_uint(f);
  return (u + 0x7fffu + ((u >> 16) & 1u)) >> 16;   // RNE
}
__device__ __forceinline__ unsigned pk2(float lo, float hi) {
  return bf16rn(lo) | (bf16rn(hi) << 16);
}

__global__ void prep(const float* __restrict__ W0, const float* __restrict__ W1,
                     const float* __restrict__ W2, const float* __restrict__ W3,
                     unsigned* __restrict__ wsu) {
  int tid = blockIdx.x * blockDim.x + threadIdx.x;
  int stride = gridDim.x * blockDim.x;
  for (int i = tid; i < 272 * 128; i += stride) {     // W0T
    int k = i >> 7, m = i & 127;
    float lo = 0.f, hi = 0.f;
    if (k < DD) { lo = W0[(2 * m) * DD + k]; hi = W0[(2 * m + 1) * DD + k]; }
    wsu[WS_W0B + i] = pk2(lo, hi);
  }
  for (int i = tid; i < 256 * 128; i += stride) {     // W1T, W2T
    int k = i >> 7, m = i & 127;
    wsu[WS_W1B + i] = pk2(W1[(2 * m) * 256 + k], W1[(2 * m + 1) * 256 + k]);
    wsu[WS_W2B + i] = pk2(W2[(2 * m) * 256 + k], W2[(2 * m + 1) * 256 + k]);
  }
  for (int i = tid; i < 256 * 136; i += stride) {     // W3T cols 0..271
    int k = i / 136, m = i - k * 136;
    int j0 = 2 * m, j1 = 2 * m + 1;
    float lo = (j0 < DD) ? W3[j0 * 256 + k] : 0.f;
    float hi = (j1 < DD) ? W3[j1 * 256 + k] : 0.f;
    wsu[WS_W3B + i] = pk2(lo, hi);
  }
}

// 1024 thr = 16 waves = 4 waves/SIMD (2x R9's latency hiding). VGPR budget is
// 128 at this occupancy -- design holds NO register weight cache (R4-R11: any
// cache needing >128 regs spills wholesale). W1 lives in LDS bf16; W0/W2/W3
// stream from L2 as bf16 (409 KB/eval vs R9's effective 926 KB).
__global__ __launch_bounds__(NTH) void node_integrate(
    const float* __restrict__ ts, const float* __restrict__ xs,
    const float* __restrict__ a_sample,
    const float* __restrict__ b0g, const float* __restrict__ b1g,
    const float* __restrict__ b2g, const float* __restrict__ b3g,
    const unsigned* __restrict__ wsu, float* __restrict__ out) {
  extern __shared__ float sm[];
  unsigned* smu = (unsigned*)sm;
  const int b   = blockIdx.x;
  const int tid = threadIdx.x;
  const int w   = tid >> 6;    // wave 0..15
  const int l   = tid & 63;    // lane

  // ---- one-time fills ----
  for (int i = tid; i < 256; i += NTH) {
    sm[L_B0 + i] = b0g[i];
    sm[L_B1 + i] = b1g[i];
    sm[L_B2 + i] = b2g[i];
  }
  for (int i = tid; i < 272; i += NTH) sm[L_B3 + i] = (i < DD) ? b3g[i] : 0.f;
  {
    const uint4* src = (const uint4*)(wsu + WS_W1B);
    uint4* dst = (uint4*)(smu + L_W1B);
    for (int i = tid; i < 256 * 32; i += NTH) dst[i] = src[i];
  }
  {
    const float sc = a_sample[b] * expf(-0.1f * ts[0]);
    for (int i = tid; i < 272; i += NTH) {
      float v = 0.f;
      if (i < DATA) v = sc * sinf(PI_F * xs[(size_t)b * DATA + i]);
      sm[L_Y + i]  = v;
      sm[L_IN + i] = 0.f;
    }
  }
  __syncthreads();

  if (tid < DATA) out[((size_t)b * NT) * DATA + tid] = sm[L_Y + tid];

  float4* ps4 = (float4*)(sm + L_PS);                 // [16] rows of 68 float4
  const uint2* w0b2 = (const uint2*)(wsu + WS_W0B);   // [272][64] uint2
  const uint2* w2b2 = (const uint2*)(wsu + WS_W2B);   // [256][64] uint2
  const uint2* w3b2 = (const uint2*)(wsu + WS_W3B);   // [256][68] uint2
  const uint2* w1l2 = (const uint2*)(smu + L_W1B);    // LDS [256][64] uint2

#pragma unroll 1
  for (int t = 0; t < NT - 1; ++t) {
    const float dt = ts[t + 1] - ts[t];
    const float h  = dt * (1.0f / NSUB);
#pragma unroll 1
    for (int sub = 0; sub < NSUB; ++sub) {
#pragma unroll 1
      for (int st = 0; st < 3; ++st) {
        const float* finp = sm + ((st == 0) ? L_Y : L_IN);

        // ---- L0: hA = tanh(W0 @ fin + b0); streamed bf16, K=272(pad)
        {
          float4 acc; acc.x = acc.y = acc.z = acc.w = 0.f;
#pragma unroll
          for (int i = 0; i < 17; ++i) {
            const int k = w + 16 * i;           // < 272
            const uint2 u = w0b2[k * 64 + l];   // cols 4l..4l+3
            const float fk = finp[k];
            UPK(u.x, c0, c1) UPK(u.y, c2, c3)
            acc.x = fmaf(c0, fk, acc.x); acc.y = fmaf(c1, fk, acc.y);
            acc.z = fmaf(c2, fk, acc.z); acc.w = fmaf(c3, fk, acc.w);
          }
          ps4[w * 68 + l] = acc;
        }
        __syncthreads();
        if (tid < 256) {
          float sv = sm[L_B0 + tid];
#pragma unroll
          for (int ww = 0; ww < NW; ++ww) sv += sm[L_PS + ww * 272 + tid];
          sm[L_HA + tid] = tanhf(sv);
        }
        __syncthreads();

        // ---- L1: hB = tanh(W1 @ hA + b1); all from LDS bf16
        {
          float4 acc; acc.x = acc.y = acc.z = acc.w = 0.f;
#pragma unroll
          for (int i = 0; i < 16; ++i) {
            const int k = w + 16 * i;           // < 256
            const uint2 u = w1l2[k * 64 + l];
            const float fk = sm[L_HA + k];
            UPK(u.x, c0, c1) UPK(u.y, c2, c3)
            acc.x = fmaf(c0, fk, acc.x); acc.y = fmaf(c1, fk, acc.y);
            acc.z = fmaf(c2, fk, acc.z); acc.w = fmaf(c3, fk, acc.w);
          }
          ps4[w * 68 + l] = acc;
        }
        __syncthreads();
        if (tid < 256) {
          float sv = sm[L_B1 + tid];
#pragma unroll
          for (int ww = 0; ww < NW; ++ww) sv += sm[L_PS + ww * 272 + tid];
          sm[L_HB + tid] = tanhf(sv);
        }
        __syncthreads();

        // ---- L2: hA = tanh(W2 @ hB + b2); streamed bf16
        {
          float4 acc; acc.x = acc.y = acc.z = acc.w = 0.f;
#pragma unroll
          for (int i = 0; i < 16; ++i) {
            const int k = w + 16 * i;
            const uint2 u = w2b2[k * 64 + l];
            const float fk = sm[L_HB + k];
            UPK(u.x, c0, c1) UPK(u.y, c2, c3)
            acc.x = fmaf(c0, fk, acc.x); acc.y = fmaf(c1, fk, acc.y);
            acc.z = fmaf(c2, fk, acc.z); acc.w = fmaf(c3, fk, acc.w);
          }
          ps4[w * 68 + l] = acc;
        }
        __syncthreads();
        if (tid < 256) {
          float sv = sm[L_B2 + tid];
#pragma unroll
          for (int ww = 0; ww < NW; ++ww) sv += sm[L_PS + ww * 272 + tid];
          sm[L_HA + tid] = tanhf(sv);
        }
        __syncthreads();

        // ---- L3: kv = W3 @ hA + b3; streamed bf16 [256][68] uint2 rows
        {
          float4 acc;  acc.x = acc.y = acc.z = acc.w = 0.f;
          float4 accx; accx.x = accx.y = accx.z = accx.w = 0.f;
#pragma unroll
          for (int i = 0; i < 16; ++i) {
            const int k = w + 16 * i;
            const float fk = sm[L_HA + k];
            const uint2 u = w3b2[k * 68 + l];            // cols 4l..4l+3
            UPK(u.x, c0, c1) UPK(u.y, c2, c3)
            acc.x = fmaf(c0, fk, acc.x); acc.y = fmaf(c1, fk, acc.y);
            acc.z = fmaf(c2, fk, acc.z); acc.w = fmaf(c3, fk, acc.w);
            if (l < 4) {
              const uint2 ux = w3b2[k * 68 + 64 + l];    // cols 256..271
              UPK(ux.x, d0, d1) UPK(ux.y, d2, d3)
              accx.x = fmaf(d0, fk, accx.x); accx.y = fmaf(d1, fk, accx.y);
              accx.z = fmaf(d2, fk, accx.z); accx.w = fmaf(d3, fk, accx.w);
            }
          }
          ps4[w * 68 + l] = acc;
          if (l < 4) ps4[w * 68 + 64 + l] = accx;
        }
        __syncthreads();
        if (tid < DD) {
          float kv = sm[L_B3 + tid];
#pragma unroll
          for (int ww = 0; ww < NW; ++ww) kv += sm[L_PS + ww * 272 + tid];
          if (st == 0) {
            sm[L_ACC + tid] = (2.0f / 9.0f) * kv;
            sm[L_IN + tid]  = sm[L_Y + tid] + 0.5f * h * kv;
          } else if (st == 1) {
            sm[L_ACC + tid] += (1.0f / 3.0f) * kv;
            sm[L_IN + tid]   = sm[L_Y + tid] + 0.75f * h * kv;
          } else {
            sm[L_Y + tid] += h * (sm[L_ACC + tid] + (4.0f / 9.0f) * kv);
          }
        }
        __syncthreads();
      }
    }
    if (tid < DATA) out[((size_t)b * NT + (t + 1)) * DATA + tid] = sm[L_Y + tid];
  }
}

extern "C" void kernel_launch(void* const* d_in, const int* in_sizes, int n_in,
                              void* d_out, int out_size, void* d_ws, size_t ws_size,
                              hipStream_t stream) {
  const float* ts = (const float*)d_in[0];
  const float* xs = (const float*)d_in[1];
  const float* a  = (const float*)d_in[2];
  const float* W0 = (const float*)d_in[3];
  const float* b0 = (const float*)d_in[4];
  const float* W1 = (const float*)d_in[5];
  const float* b1 = (const float*)d_in[6];
  const float* W2 = (const float*)d_in[7];
  const float* b2 = (const float*)d_in[8];
  const float* W3 = (const float*)d_in[9];
  const float* b3 = (const float*)d_in[10];
  unsigned* ws = (unsigned*)d_ws;
  float* out = (float*)d_out;

  const size_t lds_bytes = LDS_WORDS * sizeof(float);
  hipFuncSetAttribute(reinterpret_cast<const void*>(node_integrate),
                      hipFuncAttributeMaxDynamicSharedMemorySize,
                      (int)lds_bytes);

  hipLaunchKernelGGL(prep, dim3(256), dim3(256), 0, stream, W0, W1, W2, W3, ws);
  hipLaunchKernelGGL(node_integrate, dim3(NB), dim3(NTH), lds_bytes, stream,
                     ts, xs, a, b0, b1, b2, b3, ws, out);
}